// Round 10
// baseline (492.967 us; speedup 1.0000x reference)
//
#include <hip/hip_runtime.h>
#include <hip/hip_bf16.h>
#include <cstdint>

// ---------------- problem constants ----------------
constexpr int BATCH = 8;
constexpr int NL = 5;
constexpr int CNTS[5] = {196608, 49152, 12288, 3072, 768};
constexpr int LOFF[5] = {0, 196608, 245760, 258048, 261120};
constexpr int PERB  = 261888;               // candidates per batch
constexpr int TOTC  = BATCH * PERB;         // 2,095,104
constexpr int PREK[5]  = {2000, 2000, 2000, 2000, 768};
constexpr int POSTK[5] = {1000, 1000, 1000, 1000, 768};
constexpr int COFF[5]  = {0, 1000, 2000, 3000, 4000};
constexpr int CONCATN  = 4768;
constexpr int SELSTRIDE = 2048;             // padded per-(b,l) selection stride
constexpr int CANDCAP   = 8192;             // total candidate capacity per (b,l)
constexpr int NREP      = 64;               // counter/region replicas per (b,l)
constexpr int REPCAP    = 512;              // slots per replica region
constexpr int NBINS     = 16384;            // score bins = float bits >> 16 (sig<=1.0 -> max 16256)
constexpr int MASKROWS  = 2000;
constexpr int MASKW     = 32;               // u64 words per mask row
constexpr int SCH       = 128;              // k_scan rows per LDS chunk
constexpr int ROWS_PER_BATCH = 4 * 2000 + 768;  // 8768
constexpr float IOU_THR = 0.7f;
constexpr float CLIPV = 4.135166556742356f; // log(1000/16)
// Exact predicate constant: fl32(inter/aden) > 0.7f  <=>  inter/aden >= TAU,
// TAU = midpoint(0.7f, nextafterf(0.7f)) = 23488103 * 2^-25 (25-bit value; tie
// at the midpoint rounds to even = upper neighbor, since 0x3F333333 is odd).
// TAU*(double)aden is exact (25+24 bits <= 53), so the double compare is exact.
constexpr double TAU = 23488103.0 / 33554432.0;

struct Ptrs {
    const float* bx[5];
    const float* sc[5];
    const float* an[5];
    const float* img;
};

// ---------------- helpers ----------------
// Wave-uniform 64-bit broadcast from lane `src` (src must be wave-uniform).
__device__ __forceinline__ unsigned long long readlane_u64(unsigned long long v, int src) {
    unsigned int lo = (unsigned int)v;
    unsigned int hi = (unsigned int)(v >> 32);
    lo = (unsigned int)__builtin_amdgcn_readlane((int)lo, src);
    hi = (unsigned int)__builtin_amdgcn_readlane((int)hi, src);
    return ((unsigned long long)hi << 32) | lo;
}

// ---------------- 1) score histogram (LDS-privatized) ----------------
__global__ __launch_bounds__(1024) void k_hist(Ptrs p, unsigned int* __restrict__ hist) {
#pragma clang fp contract(off)
    __shared__ unsigned int h2[NBINS / 2];
    constexpr int CLI[11] = {0, 0, 0, 0, 0, 0, 1, 1, 2, 3, 4};
    constexpr int COF[11] = {0, 32768, 65536, 98304, 131072, 163840, 0, 24576, 0, 0, 0};
    constexpr int CLN[11] = {32768, 32768, 32768, 32768, 32768, 32768, 24576, 24576, 12288, 3072, 768};
    int blk = blockIdx.x;
    int b = blk / 11, c = blk % 11;
    int li = CLI[c], off = COF[c], len = CLN[c];
    int tid = threadIdx.x;
    for (int i = tid; i < NBINS / 2; i += 1024) h2[i] = 0;
    __syncthreads();
    const float* sp = p.sc[li] + (size_t)b * CNTS[li] + off;
    for (int i = tid; i < len; i += 1024) {
        float s = sp[i];
        float sig = 1.0f / (1.0f + expf(-s));
        unsigned int bin = __float_as_uint(sig) >> 16;
        atomicAdd(&h2[bin >> 1], 1u << ((bin & 1) << 4));
    }
    __syncthreads();
    unsigned int* H = hist + (size_t)(b * NL + li) * NBINS;
    for (int i = tid; i < NBINS / 2; i += 1024) {
        unsigned int v = h2[i];
        if (v & 0xFFFFu) atomicAdd(&H[2 * i], v & 0xFFFFu);
        if (v >> 16) atomicAdd(&H[2 * i + 1], v >> 16);
    }
}

// ---------------- 2) find threshold bin per (b,l) ----------------
__global__ void k_findbin(const unsigned int* __restrict__ hist, int* __restrict__ T) {
    int bl = blockIdx.x;
    int li = bl % NL;
    unsigned int K = (unsigned int)PREK[li];
    __shared__ unsigned int csum[256];
    const unsigned int* h = hist + (size_t)bl * NBINS;
    int tid = threadIdx.x;  // 256 threads, 64 bins each
    unsigned int s = 0;
    for (int k = 0; k < 64; ++k) s += h[tid * 64 + k];
    csum[tid] = s;
    __syncthreads();
    if (tid == 0) {
        unsigned int cum = 0;
        int t = 0;
        for (int c = 255; c >= 0; --c) {
            if (cum + csum[c] >= K) {
                for (int bin = c * 64 + 63; bin >= c * 64; --bin) {
                    cum += h[bin];
                    if (cum >= K) { t = bin; break; }
                }
                break;
            }
            cum += csum[c];
        }
        T[bl] = t;
    }
}

// ---------------- 3) compact candidates >= threshold bin ----------------
__global__ void k_compact(Ptrs p, const int* __restrict__ T,
                          unsigned long long* __restrict__ cand, unsigned int* __restrict__ cntR) {
#pragma clang fp contract(off)
    int g = blockIdx.x * blockDim.x + threadIdx.x;
    if (g >= TOTC) return;
    int b = g / PERB;
    int r = g - b * PERB;
    int li;
    if      (r < LOFF[1]) li = 0;
    else if (r < LOFF[2]) li = 1;
    else if (r < LOFF[3]) li = 2;
    else if (r < LOFF[4]) li = 3;
    else                  li = 4;
    int i = r - LOFF[li];
    int bl = b * NL + li;
    int rep = blockIdx.x & (NREP - 1);

    float s = p.sc[li][(size_t)b * CNTS[li] + i];
    float sig = 1.0f / (1.0f + expf(-s));
    unsigned int bits = __float_as_uint(sig);
    bool pass = ((int)(bits >> 16) >= T[bl]);
    unsigned long long ball = __ballot(pass);
    int lane = threadIdx.x & 63;
    unsigned int base = 0;
    if (lane == 0 && ball != 0ull)
        base = atomicAdd(&cntR[rep * 64 + bl], (unsigned int)__popcll(ball));
    base = __shfl((int)base, 0);
    if (pass) {
        unsigned int pos = base + (unsigned int)__popcll(ball & ((1ull << lane) - 1ull));
        if (pos < REPCAP)
            cand[((size_t)bl * NREP + rep) * REPCAP + pos] =
                ((unsigned long long)bits << 32) | (unsigned long long)(0xFFFFFFFFu - (unsigned int)i);
    }
}

// ---------------- 4) rank-by-counting selection + decode (replaces bitonic) ----------------
// Keys are unique -> rank(i) = #{j: key_j > key_i} is a bijection onto 0..n-1.
// Each thread holds NH candidate keys in registers and sweeps all n keys once
// via same-address LDS broadcast reads (conflict-free); candidates with
// rank < K decode+clip their box and scatter straight to sorted slot `rank`.
// 2 barriers total vs ~78 for the bitonic. Also emits per-candidate area
// (same expression/rounding k_mask used) for k_mask to consume.
template <int NH>
__device__ __forceinline__ void rank_emit(const unsigned long long* keys, int n, int K, int tid,
                                          const float4* bxp, const float4* anp,
                                          float hmax, float wmax,
                                          float* sels_o, float4* selb_o, float* selA_o) {
#pragma clang fp contract(off)
    unsigned long long myk[NH];
    int rnk[NH];
#pragma unroll
    for (int h = 0; h < NH; ++h) {
        int idx = tid + h * 1024;
        myk[h] = (idx < n) ? keys[idx] : ~0ull;
        rnk[h] = 0;
    }
    int j = 0;
    for (; j + 4 <= n; j += 4) {
        unsigned long long k0 = keys[j], k1 = keys[j + 1], k2 = keys[j + 2], k3 = keys[j + 3];
#pragma unroll
        for (int h = 0; h < NH; ++h)
            rnk[h] += (int)(k0 > myk[h]) + (int)(k1 > myk[h]) +
                      (int)(k2 > myk[h]) + (int)(k3 > myk[h]);
    }
    for (; j < n; ++j) {
        unsigned long long kj = keys[j];
#pragma unroll
        for (int h = 0; h < NH; ++h) rnk[h] += (int)(kj > myk[h]);
    }
#pragma unroll
    for (int h = 0; h < NH; ++h) {
        int idx = tid + h * 1024;
        int r = rnk[h];
        if (idx < n && r < K) {
            unsigned long long kk = myk[h];
            unsigned int gi = 0xFFFFFFFFu - (unsigned int)(kk & 0xFFFFFFFFull);
            const float4 e = bxp[gi];
            const float4 a = anp[gi];
            float dy = e.x, dx = e.y;
            float dh = fminf(e.z, CLIPV), dw = fminf(e.w, CLIPV);
            float ah = a.z - a.x, aw = a.w - a.y;
            float ayc = a.x + 0.5f * ah, axc = a.y + 0.5f * aw;
            float yc = dy * ah + ayc, xc = dx * aw + axc;
            float hh = expf(dh) * ah, ww = expf(dw) * aw;
            float y0 = yc - 0.5f * hh, x0 = xc - 0.5f * ww;
            float y1 = yc + 0.5f * hh, x1 = xc + 0.5f * ww;
            y0 = fminf(fmaxf(y0, 0.f), hmax);
            x0 = fminf(fmaxf(x0, 0.f), wmax);
            y1 = fminf(fmaxf(y1, 0.f), hmax);
            x1 = fminf(fmaxf(x1, 0.f), wmax);
            sels_o[r] = __uint_as_float((unsigned int)(kk >> 32));
            selb_o[r] = make_float4(y0, x0, y1, x1);
            selA_o[r] = (y1 - y0) * (x1 - x0);
        }
    }
}

__global__ __launch_bounds__(1024) void k_sortsel(const unsigned long long* __restrict__ cand,
                                                  const unsigned int* __restrict__ cntR, Ptrs p,
                                                  float4* __restrict__ selb, float* __restrict__ sels,
                                                  float* __restrict__ selA) {
    __shared__ unsigned long long keys[CANDCAP];  // 64 KiB
    __shared__ int pref[NREP + 1];
    int bl = blockIdx.x;
    int tid = threadIdx.x;
    int b = bl / NL, li = bl % NL;
    int K = PREK[li];
    if (tid == 0) {
        int run = 0;
        for (int rp = 0; rp < NREP; ++rp) {
            pref[rp] = run;
            int c = min((int)cntR[rp * 64 + bl], REPCAP);
            if (run + c > CANDCAP) c = CANDCAP - run;
            run += c;
        }
        pref[NREP] = run;
    }
    __syncthreads();
    int n = pref[NREP];
    for (int rp = 0; rp < NREP; ++rp) {
        int base = pref[rp], c = pref[rp + 1] - pref[rp];
        const unsigned long long* src = cand + ((size_t)bl * NREP + rp) * REPCAP;
        for (int j = tid; j < c; j += 1024) keys[base + j] = src[j];
    }
    __syncthreads();

    int nn = CNTS[li];
    float hmax = p.img[b * 2 + 0];
    float wmax = p.img[b * 2 + 1];
    const float4* bxp = reinterpret_cast<const float4*>(p.bx[li]) + (size_t)b * nn;
    const float4* anp = reinterpret_cast<const float4*>(p.an[li]) + (size_t)b * nn;
    float* so = sels + (size_t)bl * SELSTRIDE;
    float4* bo = selb + (size_t)bl * SELSTRIDE;
    float* ao = selA + (size_t)bl * SELSTRIDE;
    int nh = (n + 1023) >> 10;
    if (nh <= 2)      rank_emit<2>(keys, n, K, tid, bxp, anp, hmax, wmax, so, bo, ao);
    else if (nh <= 4) rank_emit<4>(keys, n, K, tid, bxp, anp, hmax, wmax, so, bo, ao);
    else              rank_emit<8>(keys, n, K, tid, bxp, anp, hmax, wmax, so, bo, ao);
}

// ---------------- 5) build triangular suppression bitmask ----------------
// Division-free exact predicate: fl(inter/aden) > 0.7f <=> (double)inter >=
// TAU*(double)aden (see TAU derivation above). Areas read from selA
// (precomputed in k_sortsel with identical expression/rounding).
__global__ void k_mask(const float4* __restrict__ selb, const float* __restrict__ selA,
                       unsigned long long* __restrict__ mask) {
#pragma clang fp contract(off)
    int rg = blockIdx.x;
    int b = rg / ROWS_PER_BATCH;
    int rem = rg - b * ROWS_PER_BATCH;
    int li, i;
    if (rem < 8000) { li = rem / 2000; i = rem - li * 2000; }
    else            { li = 4; i = rem - 8000; }
    int bl = b * NL + li;
    int K = PREK[li];
    const float4* bb = selb + (size_t)bl * SELSTRIDE;
    const float* aA = selA + (size_t)bl * SELSTRIDE;
    float4 bi = bb[i];
    float ai = aA[i];
    int tid = threadIdx.x;  // 256
    unsigned long long* mrow = mask + ((size_t)bl * MASKROWS + i) * MASKW;
    for (int cb = (i >> 6) << 6; cb < K; cb += 256) {
        int c = cb + tid;
        bool sup = false;
        if (c > i && c < K) {
            float4 bj = bb[c];
            float aj = aA[c];
            float iy = fmaxf(0.f, fminf(bi.z, bj.z) - fmaxf(bi.x, bj.x));
            float ix = fmaxf(0.f, fminf(bi.w, bj.w) - fmaxf(bi.y, bj.y));
            float inter = iy * ix;
            float aden = ai + aj - inter + 1e-8f;
            sup = ((double)inter >= TAU * (double)aden);
        }
        unsigned long long bal = __ballot(sup);
        int wb = cb + (tid & ~63);  // wave's base column
        if ((tid & 63) == 0 && wb < K) mrow[wb >> 6] = bal;
    }
}

// ---------------- 6) greedy NMS scan (chunked-LDS, branchless register pipeline) ----------------
__global__ __launch_bounds__(256) void k_scan(const unsigned long long* __restrict__ mask,
                                              unsigned long long* __restrict__ kept) {
    __shared__ unsigned long long lbuf[2][SCH * MASKW];  // 2 x 32 KiB
    __shared__ int stopflag;
    int bl = blockIdx.x;
    int li = bl % NL;
    int K = PREK[li];
    int W = (K + 63) >> 6;
    int PK = POSTK[li];
    int tid = threadIdx.x;
    int lane = tid & 63;
    int wv = tid >> 6;
    const unsigned long long* m = mask + (size_t)bl * MASKROWS * MASKW;
    int nchunks = (K + SCH - 1) / SCH;

    auto load_chunk = [&](int c, int t0, int nt) {
        int rbase = c * SCH;
        int nrows = min(SCH, K - rbase);
        int nu2 = nrows * (MASKW / 2);  // ulonglong2 elements
        const ulonglong2* src = reinterpret_cast<const ulonglong2*>(m + (size_t)rbase * MASKW);
        ulonglong2* dst = reinterpret_cast<ulonglong2*>(lbuf[c & 1]);
        if (tid >= t0)
            for (int j = tid - t0; j < nu2; j += nt) dst[j] = src[j];
    };

    if (tid == 0) stopflag = 0;
    load_chunk(0, 0, 256);
    __syncthreads();

    unsigned long long removed = 0, local = 0;
    int keptcnt = 0;
    for (int c = 0; c < nchunks; ++c) {
        if (c + 1 < nchunks) load_chunk(c + 1, 64, 192);  // waves 1-3 prefetch
        if (wv == 0) {
            const unsigned long long* ch = lbuf[c & 1];
            int rbase = c * SCH;
            int nrows = min(SCH, K - rbase);  // multiple of 8

            unsigned long long rvA[8], rgA[8], rvB[8], rgB[8];
            auto loadw = [&](unsigned long long (&rv)[8], unsigned long long (&rg)[8], int w0) {
                int g = (rbase + w0) >> 6;
#pragma unroll
                for (int k2 = 0; k2 < 8; ++k2) {
                    rv[k2] = ch[(w0 + k2) * MASKW + (lane & (MASKW - 1))];
                    rg[k2] = ch[(w0 + k2) * MASKW + g];  // same addr all lanes -> broadcast
                }
            };
            auto procw = [&](unsigned long long (&rv)[8], unsigned long long (&rg)[8], int w0) {
                int ii0 = rbase + w0;
                int g = ii0 >> 6;
                if ((ii0 & 63) == 0) local = readlane_u64(removed, g);  // group resync
                unsigned long long gemask = (lane >= g) ? ~0ull : 0ull;
#pragma unroll
                for (int k2 = 0; k2 < 8; ++k2) {
                    bool keptb = ((local >> ((ii0 & 63) + k2)) & 1ull) == 0ull;  // uniform
                    unsigned long long sel = keptb ? ~0ull : 0ull;
                    removed |= rv[k2] & sel & gemask;  // low words of row are garbage: gemask
                    local |= rg[k2] & sel;             // word g of row: bits<=row are 0
                    keptcnt += keptb ? 1 : 0;
                }
            };

            loadw(rvA, rgA, 0);
            for (int w0 = 0; w0 < nrows; w0 += 16) {
                if (w0 + 8 < nrows) loadw(rvB, rgB, w0 + 8);
                procw(rvA, rgA, w0);
                if (w0 + 8 < nrows) {
                    if (w0 + 16 < nrows) loadw(rvA, rgA, w0 + 16);
                    procw(rvB, rgB, w0 + 8);
                }
            }
            if (keptcnt >= PK && c + 1 < nchunks) {
                // rows beyond this chunk can't reach the output: mark suppressed
                if (lane >= (c + 1) * (SCH / 64)) removed = ~0ull;
                if (lane == 0) stopflag = 1;
            }
        }
        __syncthreads();
        if (stopflag) break;
    }
    if (wv == 0 && lane < W) {
        int remn = K - lane * 64;
        unsigned long long valid = (remn >= 64) ? ~0ull : ((1ull << remn) - 1ull);
        kept[bl * MASKW + lane] = (~removed) & valid;
    }
}

// ---------------- 7) per-level output: compact kept, zero-pad, concat ----------------
__global__ void k_lvlout(const unsigned long long* __restrict__ kept,
                         const float* __restrict__ sels, const float4* __restrict__ selb,
                         float* __restrict__ cscores, float4* __restrict__ cboxes) {
    int bl = blockIdx.x;
    int b = bl / NL, li = bl % NL;
    int K = PREK[li];
    int W = (K + 63) >> 6;
    int PK = POSTK[li];
    int tid = threadIdx.x;  // 256
    __shared__ unsigned long long kw[32];
    __shared__ int pref[33];
    if (tid < W) kw[tid] = kept[bl * MASKW + tid];
    __syncthreads();
    if (tid == 0) {
        int run = 0;
        for (int w = 0; w < W; ++w) { pref[w] = run; run += __popcll(kw[w]); }
        pref[W] = run;
    }
    __syncthreads();
    int total = pref[W];
    int nused = min(total, PK);
    float* cs = cscores + (size_t)b * CONCATN + COFF[li];
    float4* cbx = cboxes + (size_t)b * CONCATN + COFF[li];
    if (tid < W) {
        int rank = pref[tid];
        unsigned long long w64 = kw[tid];
        while (w64 != 0ull && rank < PK) {
            int j = __ffsll(w64) - 1;
            w64 &= (w64 - 1);
            int pidx = tid * 64 + j;
            cs[rank] = sels[(size_t)bl * SELSTRIDE + pidx];
            cbx[rank] = selb[(size_t)bl * SELSTRIDE + pidx];
            ++rank;
        }
    }
    for (int r = nused + tid; r < PK; r += 256) {
        cs[r] = 0.f;
        cbx[r] = make_float4(0.f, 0.f, 0.f, 0.f);
    }
}

// ---------------- 8) final per-batch top-1000: rank 5 sorted runs by counting ----------------
__global__ __launch_bounds__(1024) void k_final(const float* __restrict__ cscores,
                                                const float4* __restrict__ cboxes,
                                                float* __restrict__ out) {
    __shared__ unsigned long long keys[CONCATN];
    int b = blockIdx.x;
    int tid = threadIdx.x;
    const float* cs = cscores + (size_t)b * CONCATN;
    for (int i = tid; i < CONCATN; i += 1024)
        keys[i] = (((unsigned long long)__float_as_uint(cs[i]) << 32) |
                   (unsigned long long)(0xFFFFFFFFu - (unsigned int)i));
    __syncthreads();
    const float4* cbx = cboxes + (size_t)b * CONCATN;
    float4* ob = reinterpret_cast<float4*>(out) + (size_t)b * 1000;
    float* os = out + (size_t)BATCH * 1000 * 4 + (size_t)b * 1000;
    for (int i = tid; i < CONCATN; i += 1024) {
        unsigned long long k = keys[i];
        int myli = min(i / 1000, 4);
        int rank = i - COFF[myli];  // own run strictly desc -> own index = count-greater
#pragma unroll
        for (int r = 0; r < NL; ++r) {
            if (r == myli) continue;
            const unsigned long long* run = keys + COFF[r];
            int lo = 0, hi = POSTK[r];
            while (lo < hi) {  // count of elements > k in a descending run
                int mid = (lo + hi) >> 1;
                if (run[mid] > k) lo = mid + 1; else hi = mid;
            }
            rank += lo;
        }
        if (rank < 1000) {
            ob[rank] = cbx[i];
            os[rank] = __uint_as_float((unsigned int)(k >> 32));
        }
    }
}

// ---------------- launcher ----------------
extern "C" void kernel_launch(void* const* d_in, const int* in_sizes, int n_in,
                              void* d_out, int out_size, void* d_ws, size_t ws_size,
                              hipStream_t stream) {
    Ptrs p;
    // setup_inputs() dict order: (boxes,scores,anchors) per level, then image_shape.
    bool dict_order = (in_sizes[2] == 6291456);
    for (int l = 0; l < 5; ++l) {
        if (dict_order) {
            p.bx[l] = (const float*)d_in[3 * l + 0];
            p.sc[l] = (const float*)d_in[3 * l + 1];
            p.an[l] = (const float*)d_in[3 * l + 2];
        } else {
            p.bx[l] = (const float*)d_in[l];
            p.sc[l] = (const float*)d_in[5 + l];
            p.an[l] = (const float*)d_in[10 + l];
        }
    }
    p.img = (const float*)d_in[15];

    char* ws = (char*)d_ws;
    size_t off = 0;
    auto walloc = [&](size_t sz) -> void* {
        void* r = ws + off;
        off = (off + sz + 255) & ~(size_t)255;
        return r;
    };
    unsigned int* hist         = (unsigned int*)walloc((size_t)40 * NBINS * 4);
    unsigned int* cntR         = (unsigned int*)walloc((size_t)NREP * 64 * 4);
    int* T                     = (int*)walloc(40 * 4);
    unsigned long long* cand   = (unsigned long long*)walloc((size_t)40 * NREP * REPCAP * 8);
    float4* selb               = (float4*)walloc((size_t)40 * SELSTRIDE * 16);
    float* sels                = (float*)walloc((size_t)40 * SELSTRIDE * 4);
    float* selA                = (float*)walloc((size_t)40 * SELSTRIDE * 4);
    unsigned long long* mask   = (unsigned long long*)walloc((size_t)40 * MASKROWS * MASKW * 8);
    unsigned long long* kept   = (unsigned long long*)walloc((size_t)40 * MASKW * 8);
    float* cscores             = (float*)walloc((size_t)BATCH * CONCATN * 4);
    float4* cboxes             = (float4*)walloc((size_t)BATCH * CONCATN * 16);
    (void)ws_size;

    hipMemsetAsync(hist, 0, (size_t)40 * NBINS * 4, stream);
    hipMemsetAsync(cntR, 0, (size_t)NREP * 64 * 4, stream);

    k_hist<<<BATCH * 11, 1024, 0, stream>>>(p, hist);
    k_findbin<<<40, 256, 0, stream>>>(hist, T);
    k_compact<<<(TOTC + 255) / 256, 256, 0, stream>>>(p, T, cand, cntR);
    k_sortsel<<<40, 1024, 0, stream>>>(cand, cntR, p, selb, sels, selA);
    k_mask<<<BATCH * ROWS_PER_BATCH, 256, 0, stream>>>(selb, selA, mask);
    k_scan<<<40, 256, 0, stream>>>(mask, kept);
    k_lvlout<<<40, 256, 0, stream>>>(kept, sels, selb, cscores, cboxes);
    k_final<<<8, 1024, 0, stream>>>(cscores, cboxes, (float*)d_out);
}

// Round 11
// 420.324 us; speedup vs baseline: 1.1728x; 1.1728x over previous
//
#include <hip/hip_runtime.h>
#include <hip/hip_bf16.h>
#include <cstdint>

// ---------------- problem constants ----------------
constexpr int BATCH = 8;
constexpr int NL = 5;
constexpr int CNTS[5] = {196608, 49152, 12288, 3072, 768};
constexpr int LOFF[5] = {0, 196608, 245760, 258048, 261120};
constexpr int PERB  = 261888;               // candidates per batch
constexpr int TOTC  = BATCH * PERB;         // 2,095,104
constexpr int PREK[5]  = {2000, 2000, 2000, 2000, 768};
constexpr int POSTK[5] = {1000, 1000, 1000, 1000, 768};
constexpr int COFF[5]  = {0, 1000, 2000, 3000, 4000};
constexpr int CONCATN  = 4768;
constexpr int SELSTRIDE = 2048;             // padded per-(b,l) selection stride
constexpr int CANDCAP   = 8192;             // total candidate capacity per (b,l)
constexpr int NREP      = 64;               // counter/region replicas per (b,l)
constexpr int REPCAP    = 512;              // slots per replica region
constexpr int NBINS     = 16384;            // score bins = float bits >> 16 (sig<=1.0 -> max 16256)
constexpr int NSUB      = 12;               // rank sub-blocks per (b,l): covers n <= 3072 in primary pass
constexpr int MASKROWS  = 2000;
constexpr int MASKW     = 32;               // u64 words per mask row
constexpr int SCH       = 128;              // k_scan rows per LDS chunk
constexpr int ROWS_PER_BATCH = 4 * 2000 + 768;  // 8768
constexpr float IOU_THR = 0.7f;
constexpr float CLIPV = 4.135166556742356f; // log(1000/16)
// Exact predicate constant: fl32(inter/aden) > 0.7f  <=>  inter/aden >= TAU,
// TAU = midpoint(0.7f, nextafterf(0.7f)) = 23488103 * 2^-25 (25-bit value; tie
// at the midpoint rounds to even = upper neighbor, since 0x3F333333 is odd).
// TAU*(double)aden is exact (25+24 bits <= 53), so the double compare is exact.
constexpr double TAU = 23488103.0 / 33554432.0;

struct Ptrs {
    const float* bx[5];
    const float* sc[5];
    const float* an[5];
    const float* img;
};

// ---------------- helpers ----------------
// Wave-uniform 64-bit broadcast from lane `src` (src must be wave-uniform).
__device__ __forceinline__ unsigned long long readlane_u64(unsigned long long v, int src) {
    unsigned int lo = (unsigned int)v;
    unsigned int hi = (unsigned int)(v >> 32);
    lo = (unsigned int)__builtin_amdgcn_readlane((int)lo, src);
    hi = (unsigned int)__builtin_amdgcn_readlane((int)hi, src);
    return ((unsigned long long)hi << 32) | lo;
}

// ---------------- 1) score histogram (LDS-privatized) ----------------
__global__ __launch_bounds__(1024) void k_hist(Ptrs p, unsigned int* __restrict__ hist) {
#pragma clang fp contract(off)
    __shared__ unsigned int h2[NBINS / 2];
    constexpr int CLI[11] = {0, 0, 0, 0, 0, 0, 1, 1, 2, 3, 4};
    constexpr int COF[11] = {0, 32768, 65536, 98304, 131072, 163840, 0, 24576, 0, 0, 0};
    constexpr int CLN[11] = {32768, 32768, 32768, 32768, 32768, 32768, 24576, 24576, 12288, 3072, 768};
    int blk = blockIdx.x;
    int b = blk / 11, c = blk % 11;
    int li = CLI[c], off = COF[c], len = CLN[c];
    int tid = threadIdx.x;
    for (int i = tid; i < NBINS / 2; i += 1024) h2[i] = 0;
    __syncthreads();
    const float* sp = p.sc[li] + (size_t)b * CNTS[li] + off;
    for (int i = tid; i < len; i += 1024) {
        float s = sp[i];
        float sig = 1.0f / (1.0f + expf(-s));
        unsigned int bin = __float_as_uint(sig) >> 16;
        atomicAdd(&h2[bin >> 1], 1u << ((bin & 1) << 4));
    }
    __syncthreads();
    unsigned int* H = hist + (size_t)(b * NL + li) * NBINS;
    for (int i = tid; i < NBINS / 2; i += 1024) {
        unsigned int v = h2[i];
        if (v & 0xFFFFu) atomicAdd(&H[2 * i], v & 0xFFFFu);
        if (v >> 16) atomicAdd(&H[2 * i + 1], v >> 16);
    }
}

// ---------------- 2) find threshold bin per (b,l) ----------------
__global__ void k_findbin(const unsigned int* __restrict__ hist, int* __restrict__ T) {
    int bl = blockIdx.x;
    int li = bl % NL;
    unsigned int K = (unsigned int)PREK[li];
    __shared__ unsigned int csum[256];
    const unsigned int* h = hist + (size_t)bl * NBINS;
    int tid = threadIdx.x;  // 256 threads, 64 bins each
    unsigned int s = 0;
    for (int k = 0; k < 64; ++k) s += h[tid * 64 + k];
    csum[tid] = s;
    __syncthreads();
    if (tid == 0) {
        unsigned int cum = 0;
        int t = 0;
        for (int c = 255; c >= 0; --c) {
            if (cum + csum[c] >= K) {
                for (int bin = c * 64 + 63; bin >= c * 64; --bin) {
                    cum += h[bin];
                    if (cum >= K) { t = bin; break; }
                }
                break;
            }
            cum += csum[c];
        }
        T[bl] = t;
    }
}

// ---------------- 3) compact candidates >= threshold bin ----------------
__global__ void k_compact(Ptrs p, const int* __restrict__ T,
                          unsigned long long* __restrict__ cand, unsigned int* __restrict__ cntR) {
#pragma clang fp contract(off)
    int g = blockIdx.x * blockDim.x + threadIdx.x;
    if (g >= TOTC) return;
    int b = g / PERB;
    int r = g - b * PERB;
    int li;
    if      (r < LOFF[1]) li = 0;
    else if (r < LOFF[2]) li = 1;
    else if (r < LOFF[3]) li = 2;
    else if (r < LOFF[4]) li = 3;
    else                  li = 4;
    int i = r - LOFF[li];
    int bl = b * NL + li;
    int rep = blockIdx.x & (NREP - 1);

    float s = p.sc[li][(size_t)b * CNTS[li] + i];
    float sig = 1.0f / (1.0f + expf(-s));
    unsigned int bits = __float_as_uint(sig);
    bool pass = ((int)(bits >> 16) >= T[bl]);
    unsigned long long ball = __ballot(pass);
    int lane = threadIdx.x & 63;
    unsigned int base = 0;
    if (lane == 0 && ball != 0ull)
        base = atomicAdd(&cntR[rep * 64 + bl], (unsigned int)__popcll(ball));
    base = __shfl((int)base, 0);
    if (pass) {
        unsigned int pos = base + (unsigned int)__popcll(ball & ((1ull << lane) - 1ull));
        if (pos < REPCAP)
            cand[((size_t)bl * NREP + rep) * REPCAP + pos] =
                ((unsigned long long)bits << 32) | (unsigned long long)(0xFFFFFFFFu - (unsigned int)i);
    }
}

// ---------------- 4a) gather replica regions into a dense key array ----------------
__global__ __launch_bounds__(256) void k_gather(const unsigned long long* __restrict__ cand,
                                                const unsigned int* __restrict__ cntR,
                                                unsigned long long* __restrict__ dense,
                                                int* __restrict__ nArr) {
    __shared__ int pref[NREP + 1];
    int bl = blockIdx.x;
    int tid = threadIdx.x;
    if (tid == 0) {
        int run = 0;
        for (int rp = 0; rp < NREP; ++rp) {
            pref[rp] = run;
            int c = min((int)cntR[rp * 64 + bl], REPCAP);
            if (run + c > CANDCAP) c = CANDCAP - run;
            run += c;
        }
        pref[NREP] = run;
        nArr[bl] = run;
    }
    __syncthreads();
    int n = pref[NREP];
    unsigned long long* d = dense + (size_t)bl * CANDCAP;
    for (int rp = 0; rp < NREP; ++rp) {
        int base = pref[rp], c = pref[rp + 1] - pref[rp];
        const unsigned long long* src = cand + ((size_t)bl * NREP + rp) * REPCAP;
        for (int j = tid; j < c; j += 256) d[base + j] = src[j];
    }
    int npad = (n + 63) & ~63;
    for (int j = n + tid; j < npad; j += 256) d[j] = 0ull;  // 0 < any real key (sig>0)
}

// ---------------- 4b) rank-by-counting + decode (12 sub-blocks per (b,l)) ----------------
// Keys unique -> rank(i) = #{j: key_j > key_i} is a bijection onto 0..n-1.
// Each wave sweeps the dense array in 64-key register tiles: ONE coalesced
// global load per tile (L1/L2-hit), then v_readlane broadcasts each key from
// registers -- zero LDS ops, pure-VALU inner loop (2 readlane + cmp64 + addc),
// tiles double-buffered so the load hides under the 64-broadcast loop.
// Candidates with rank < K decode+clip and scatter straight to slot rank.
__global__ __launch_bounds__(256) void k_rank(const unsigned long long* __restrict__ dense,
                                              const int* __restrict__ nArr, Ptrs p,
                                              float4* __restrict__ selb, float* __restrict__ sels,
                                              float* __restrict__ selA) {
#pragma clang fp contract(off)
    int blk = blockIdx.x;
    int bl = blk / NSUB, s = blk % NSUB;
    int b = bl / NL, li = bl % NL;
    int K = PREK[li];
    int tid = threadIdx.x, lane = tid & 63;
    int n = nArr[bl];
    const unsigned long long* d = dense + (size_t)bl * CANDCAP;
    int nt = (n + 63) >> 6;

    int nn = CNTS[li];
    float hmax = p.img[b * 2 + 0];
    float wmax = p.img[b * 2 + 1];
    const float4* bxp = reinterpret_cast<const float4*>(p.bx[li]) + (size_t)b * nn;
    const float4* anp = reinterpret_cast<const float4*>(p.an[li]) + (size_t)b * nn;
    float* so = sels + (size_t)bl * SELSTRIDE;
    float4* bo = selb + (size_t)bl * SELSTRIDE;
    float* ao = selA + (size_t)bl * SELSTRIDE;

    auto process = [&](int idx) {
        unsigned long long myk = (idx < n) ? d[idx] : ~0ull;
        int rnk = 0;
        const unsigned long long* g = d + lane;
        unsigned long long cur = (nt > 0) ? g[0] : 0ull, nxt = 0ull;
        for (int t = 0; t < nt; ++t) {
            if (t + 1 < nt) nxt = g[(size_t)(t + 1) * 64];  // prefetch next tile
#pragma unroll 16
            for (int j = 0; j < 64; ++j) {
                unsigned long long bc = readlane_u64(cur, j);
                rnk += (int)(bc > myk);
            }
            cur = nxt;
        }
        if (idx < n && rnk < K) {
            unsigned long long kk = myk;
            unsigned int gi = 0xFFFFFFFFu - (unsigned int)(kk & 0xFFFFFFFFull);
            const float4 e = bxp[gi];
            const float4 a = anp[gi];
            float dy = e.x, dx = e.y;
            float dh = fminf(e.z, CLIPV), dw = fminf(e.w, CLIPV);
            float ah = a.z - a.x, aw = a.w - a.y;
            float ayc = a.x + 0.5f * ah, axc = a.y + 0.5f * aw;
            float yc = dy * ah + ayc, xc = dx * aw + axc;
            float hh = expf(dh) * ah, ww = expf(dw) * aw;
            float y0 = yc - 0.5f * hh, x0 = xc - 0.5f * ww;
            float y1 = yc + 0.5f * hh, x1 = xc + 0.5f * ww;
            y0 = fminf(fmaxf(y0, 0.f), hmax);
            x0 = fminf(fmaxf(x0, 0.f), wmax);
            y1 = fminf(fmaxf(y1, 0.f), hmax);
            x1 = fminf(fmaxf(x1, 0.f), wmax);
            so[rnk] = __uint_as_float((unsigned int)(kk >> 32));
            bo[rnk] = make_float4(y0, x0, y1, x1);
            ao[rnk] = (y1 - y0) * (x1 - x0);
        }
    };

    process(s * 256 + tid);
    if (s == NSUB - 1)  // correctness tail for pathological n > NSUB*256
        for (int b2 = NSUB * 256; b2 < n; b2 += 256) process(b2 + tid);
}

// ---------------- 5) build triangular suppression bitmask ----------------
// Division-free exact predicate: fl(inter/aden) > 0.7f <=> (double)inter >=
// TAU*(double)aden. Areas read from selA (identical expression/rounding).
__global__ void k_mask(const float4* __restrict__ selb, const float* __restrict__ selA,
                       unsigned long long* __restrict__ mask) {
#pragma clang fp contract(off)
    int rg = blockIdx.x;
    int b = rg / ROWS_PER_BATCH;
    int rem = rg - b * ROWS_PER_BATCH;
    int li, i;
    if (rem < 8000) { li = rem / 2000; i = rem - li * 2000; }
    else            { li = 4; i = rem - 8000; }
    int bl = b * NL + li;
    int K = PREK[li];
    const float4* bb = selb + (size_t)bl * SELSTRIDE;
    const float* aA = selA + (size_t)bl * SELSTRIDE;
    float4 bi = bb[i];
    float ai = aA[i];
    int tid = threadIdx.x;  // 256
    unsigned long long* mrow = mask + ((size_t)bl * MASKROWS + i) * MASKW;
    for (int cb = (i >> 6) << 6; cb < K; cb += 256) {
        int c = cb + tid;
        bool sup = false;
        if (c > i && c < K) {
            float4 bj = bb[c];
            float aj = aA[c];
            float iy = fmaxf(0.f, fminf(bi.z, bj.z) - fmaxf(bi.x, bj.x));
            float ix = fmaxf(0.f, fminf(bi.w, bj.w) - fmaxf(bi.y, bj.y));
            float inter = iy * ix;
            float aden = ai + aj - inter + 1e-8f;
            sup = ((double)inter >= TAU * (double)aden);
        }
        unsigned long long bal = __ballot(sup);
        int wb = cb + (tid & ~63);  // wave's base column
        if ((tid & 63) == 0 && wb < K) mrow[wb >> 6] = bal;
    }
}

// ---------------- 6) greedy NMS scan (chunked-LDS, branchless register pipeline) ----------------
__global__ __launch_bounds__(256) void k_scan(const unsigned long long* __restrict__ mask,
                                              unsigned long long* __restrict__ kept) {
    __shared__ unsigned long long lbuf[2][SCH * MASKW];  // 2 x 32 KiB
    __shared__ int stopflag;
    int bl = blockIdx.x;
    int li = bl % NL;
    int K = PREK[li];
    int W = (K + 63) >> 6;
    int PK = POSTK[li];
    int tid = threadIdx.x;
    int lane = tid & 63;
    int wv = tid >> 6;
    const unsigned long long* m = mask + (size_t)bl * MASKROWS * MASKW;
    int nchunks = (K + SCH - 1) / SCH;

    auto load_chunk = [&](int c, int t0, int nt) {
        int rbase = c * SCH;
        int nrows = min(SCH, K - rbase);
        int nu2 = nrows * (MASKW / 2);  // ulonglong2 elements
        const ulonglong2* src = reinterpret_cast<const ulonglong2*>(m + (size_t)rbase * MASKW);
        ulonglong2* dst = reinterpret_cast<ulonglong2*>(lbuf[c & 1]);
        if (tid >= t0)
            for (int j = tid - t0; j < nu2; j += nt) dst[j] = src[j];
    };

    if (tid == 0) stopflag = 0;
    load_chunk(0, 0, 256);
    __syncthreads();

    unsigned long long removed = 0, local = 0;
    int keptcnt = 0;
    for (int c = 0; c < nchunks; ++c) {
        if (c + 1 < nchunks) load_chunk(c + 1, 64, 192);  // waves 1-3 prefetch
        if (wv == 0) {
            const unsigned long long* ch = lbuf[c & 1];
            int rbase = c * SCH;
            int nrows = min(SCH, K - rbase);  // multiple of 8

            unsigned long long rvA[8], rgA[8], rvB[8], rgB[8];
            auto loadw = [&](unsigned long long (&rv)[8], unsigned long long (&rg)[8], int w0) {
                int g = (rbase + w0) >> 6;
#pragma unroll
                for (int k2 = 0; k2 < 8; ++k2) {
                    rv[k2] = ch[(w0 + k2) * MASKW + (lane & (MASKW - 1))];
                    rg[k2] = ch[(w0 + k2) * MASKW + g];  // same addr all lanes -> broadcast
                }
            };
            auto procw = [&](unsigned long long (&rv)[8], unsigned long long (&rg)[8], int w0) {
                int ii0 = rbase + w0;
                int g = ii0 >> 6;
                if ((ii0 & 63) == 0) local = readlane_u64(removed, g);  // group resync
                unsigned long long gemask = (lane >= g) ? ~0ull : 0ull;
#pragma unroll
                for (int k2 = 0; k2 < 8; ++k2) {
                    bool keptb = ((local >> ((ii0 & 63) + k2)) & 1ull) == 0ull;  // uniform
                    unsigned long long sel = keptb ? ~0ull : 0ull;
                    removed |= rv[k2] & sel & gemask;  // low words of row are garbage: gemask
                    local |= rg[k2] & sel;             // word g of row: bits<=row are 0
                    keptcnt += keptb ? 1 : 0;
                }
            };

            loadw(rvA, rgA, 0);
            for (int w0 = 0; w0 < nrows; w0 += 16) {
                if (w0 + 8 < nrows) loadw(rvB, rgB, w0 + 8);
                procw(rvA, rgA, w0);
                if (w0 + 8 < nrows) {
                    if (w0 + 16 < nrows) loadw(rvA, rgA, w0 + 16);
                    procw(rvB, rgB, w0 + 8);
                }
            }
            if (keptcnt >= PK && c + 1 < nchunks) {
                // rows beyond this chunk can't reach the output: mark suppressed
                if (lane >= (c + 1) * (SCH / 64)) removed = ~0ull;
                if (lane == 0) stopflag = 1;
            }
        }
        __syncthreads();
        if (stopflag) break;
    }
    if (wv == 0 && lane < W) {
        int remn = K - lane * 64;
        unsigned long long valid = (remn >= 64) ? ~0ull : ((1ull << remn) - 1ull);
        kept[bl * MASKW + lane] = (~removed) & valid;
    }
}

// ---------------- 7) per-level output: compact kept, zero-pad, concat ----------------
__global__ void k_lvlout(const unsigned long long* __restrict__ kept,
                         const float* __restrict__ sels, const float4* __restrict__ selb,
                         float* __restrict__ cscores, float4* __restrict__ cboxes) {
    int bl = blockIdx.x;
    int b = bl / NL, li = bl % NL;
    int K = PREK[li];
    int W = (K + 63) >> 6;
    int PK = POSTK[li];
    int tid = threadIdx.x;  // 256
    __shared__ unsigned long long kw[32];
    __shared__ int pref[33];
    if (tid < W) kw[tid] = kept[bl * MASKW + tid];
    __syncthreads();
    if (tid == 0) {
        int run = 0;
        for (int w = 0; w < W; ++w) { pref[w] = run; run += __popcll(kw[w]); }
        pref[W] = run;
    }
    __syncthreads();
    int total = pref[W];
    int nused = min(total, PK);
    float* cs = cscores + (size_t)b * CONCATN + COFF[li];
    float4* cbx = cboxes + (size_t)b * CONCATN + COFF[li];
    if (tid < W) {
        int rank = pref[tid];
        unsigned long long w64 = kw[tid];
        while (w64 != 0ull && rank < PK) {
            int j = __ffsll(w64) - 1;
            w64 &= (w64 - 1);
            int pidx = tid * 64 + j;
            cs[rank] = sels[(size_t)bl * SELSTRIDE + pidx];
            cbx[rank] = selb[(size_t)bl * SELSTRIDE + pidx];
            ++rank;
        }
    }
    for (int r = nused + tid; r < PK; r += 256) {
        cs[r] = 0.f;
        cbx[r] = make_float4(0.f, 0.f, 0.f, 0.f);
    }
}

// ---------------- 8) final per-batch top-1000: rank 5 sorted runs by counting ----------------
__global__ __launch_bounds__(1024) void k_final(const float* __restrict__ cscores,
                                                const float4* __restrict__ cboxes,
                                                float* __restrict__ out) {
    __shared__ unsigned long long keys[CONCATN];
    int b = blockIdx.x;
    int tid = threadIdx.x;
    const float* cs = cscores + (size_t)b * CONCATN;
    for (int i = tid; i < CONCATN; i += 1024)
        keys[i] = (((unsigned long long)__float_as_uint(cs[i]) << 32) |
                   (unsigned long long)(0xFFFFFFFFu - (unsigned int)i));
    __syncthreads();
    const float4* cbx = cboxes + (size_t)b * CONCATN;
    float4* ob = reinterpret_cast<float4*>(out) + (size_t)b * 1000;
    float* os = out + (size_t)BATCH * 1000 * 4 + (size_t)b * 1000;
    for (int i = tid; i < CONCATN; i += 1024) {
        unsigned long long k = keys[i];
        int myli = min(i / 1000, 4);
        int rank = i - COFF[myli];  // own run strictly desc -> own index = count-greater
#pragma unroll
        for (int r = 0; r < NL; ++r) {
            if (r == myli) continue;
            const unsigned long long* run = keys + COFF[r];
            int lo = 0, hi = POSTK[r];
            while (lo < hi) {  // count of elements > k in a descending run
                int mid = (lo + hi) >> 1;
                if (run[mid] > k) lo = mid + 1; else hi = mid;
            }
            rank += lo;
        }
        if (rank < 1000) {
            ob[rank] = cbx[i];
            os[rank] = __uint_as_float((unsigned int)(k >> 32));
        }
    }
}

// ---------------- launcher ----------------
extern "C" void kernel_launch(void* const* d_in, const int* in_sizes, int n_in,
                              void* d_out, int out_size, void* d_ws, size_t ws_size,
                              hipStream_t stream) {
    Ptrs p;
    // setup_inputs() dict order: (boxes,scores,anchors) per level, then image_shape.
    bool dict_order = (in_sizes[2] == 6291456);
    for (int l = 0; l < 5; ++l) {
        if (dict_order) {
            p.bx[l] = (const float*)d_in[3 * l + 0];
            p.sc[l] = (const float*)d_in[3 * l + 1];
            p.an[l] = (const float*)d_in[3 * l + 2];
        } else {
            p.bx[l] = (const float*)d_in[l];
            p.sc[l] = (const float*)d_in[5 + l];
            p.an[l] = (const float*)d_in[10 + l];
        }
    }
    p.img = (const float*)d_in[15];

    char* ws = (char*)d_ws;
    size_t off = 0;
    auto walloc = [&](size_t sz) -> void* {
        void* r = ws + off;
        off = (off + sz + 255) & ~(size_t)255;
        return r;
    };
    unsigned int* hist         = (unsigned int*)walloc((size_t)40 * NBINS * 4);
    unsigned int* cntR         = (unsigned int*)walloc((size_t)NREP * 64 * 4);
    int* T                     = (int*)walloc(40 * 4);
    unsigned long long* cand   = (unsigned long long*)walloc((size_t)40 * NREP * REPCAP * 8);
    unsigned long long* dense  = (unsigned long long*)walloc((size_t)40 * CANDCAP * 8);
    int* nArr                  = (int*)walloc(40 * 4);
    float4* selb               = (float4*)walloc((size_t)40 * SELSTRIDE * 16);
    float* sels                = (float*)walloc((size_t)40 * SELSTRIDE * 4);
    float* selA                = (float*)walloc((size_t)40 * SELSTRIDE * 4);
    unsigned long long* mask   = (unsigned long long*)walloc((size_t)40 * MASKROWS * MASKW * 8);
    unsigned long long* kept   = (unsigned long long*)walloc((size_t)40 * MASKW * 8);
    float* cscores             = (float*)walloc((size_t)BATCH * CONCATN * 4);
    float4* cboxes             = (float4*)walloc((size_t)BATCH * CONCATN * 16);
    (void)ws_size;

    hipMemsetAsync(hist, 0, (size_t)40 * NBINS * 4, stream);
    hipMemsetAsync(cntR, 0, (size_t)NREP * 64 * 4, stream);

    k_hist<<<BATCH * 11, 1024, 0, stream>>>(p, hist);
    k_findbin<<<40, 256, 0, stream>>>(hist, T);
    k_compact<<<(TOTC + 255) / 256, 256, 0, stream>>>(p, T, cand, cntR);
    k_gather<<<40, 256, 0, stream>>>(cand, cntR, dense, nArr);
    k_rank<<<40 * NSUB, 256, 0, stream>>>(dense, nArr, p, selb, sels, selA);
    k_mask<<<BATCH * ROWS_PER_BATCH, 256, 0, stream>>>(selb, selA, mask);
    k_scan<<<40, 256, 0, stream>>>(mask, kept);
    k_lvlout<<<40, 256, 0, stream>>>(kept, sels, selb, cscores, cboxes);
    k_final<<<8, 1024, 0, stream>>>(cscores, cboxes, (float*)d_out);
}